// Round 4
// baseline (512.430 us; speedup 1.0000x reference)
//
#include <hip/hip_runtime.h>
#include <stdint.h>

typedef __attribute__((ext_vector_type(8))) short short8;   // 8 bf16 in 4 VGPRs
typedef __attribute__((ext_vector_type(4))) float f32x4;

#define NR_ROUTED 16384      // T * TOP_K
#define NROWS     20480      // + T shared rows
#define MAXTILES  192

__device__ __forceinline__ float bf2f(unsigned short h) {
  return __uint_as_float(((unsigned)h) << 16);
}
__device__ __forceinline__ unsigned short f2bf(float f) {
  unsigned u = __float_as_uint(f);
  u = (u + 0x7FFFu + ((u >> 16) & 1u)) >> 16;   // round-to-nearest-even
  return (unsigned short)u;
}

// ------------- transpose + cast weights: [e][K][N] fp32 -> bf16 [e][1024 rows][Kd] -------------
// dst row = e*1024 + (n0+n)*n_mul + n_add  (n_mul=2 interleaves gate/up columns for fused silu)
__global__ void tcast_kernel(const float* __restrict__ src0, const float* __restrict__ src1,
                             unsigned short* __restrict__ dst, int Kd, int Nd,
                             int n_mul, int n_add) {
  __shared__ float tl[64][65];
  int tilesK = Kd >> 6;
  int tk = blockIdx.x % tilesK, tn = blockIdx.x / tilesK;
  int e = blockIdx.y;
  const float* src = (e < 32) ? (src0 + (size_t)e * Kd * Nd) : src1;
  int k0 = tk * 64, n0 = tn * 64;
  int tid = threadIdx.x;
#pragma unroll
  for (int p = 0; p < 4; ++p) {
    int f = p * 256 + tid;
    int r = f >> 4, c4 = (f & 15) * 4;
    float4 v = *(const float4*)(src + (size_t)(k0 + r) * Nd + n0 + c4);
    tl[c4 + 0][r] = v.x; tl[c4 + 1][r] = v.y; tl[c4 + 2][r] = v.z; tl[c4 + 3][r] = v.w;
  }
  __syncthreads();
#pragma unroll
  for (int p = 0; p < 4; ++p) {
    int f = p * 256 + tid;
    int n = f >> 4, kc = (f & 15) * 4;
    ushort4 o;
    o.x = f2bf(tl[n][kc + 0]); o.y = f2bf(tl[n][kc + 1]);
    o.z = f2bf(tl[n][kc + 2]); o.w = f2bf(tl[n][kc + 3]);
    *(ushort4*)(dst + ((size_t)e * 1024 + (size_t)(n0 + n) * n_mul + n_add) * Kd + k0 + kc) = o;
  }
}

// ---------------- gate-weight transpose: gwt[j4][e] = float4(gw[e][j4*4..+3]) ----------------
__global__ void gwt_kernel(const float* __restrict__ gw, float* __restrict__ gwt) {
  int idx = blockIdx.x * 256 + threadIdx.x;      // 8192 threads
  int e = idx & 31, j4 = idx >> 5;
  float4 v = *(const float4*)(gw + (size_t)e * 1024 + j4 * 4);
  *(float4*)(gwt + ((size_t)j4 * 32 + e) * 4) = v;
}

// ---------------- routing: wave = 2 tokens, lane = (tok2<<5)|expert, register top-k ----------------
__global__ __launch_bounds__(256) void routing_kernel(
    const float* __restrict__ x, const float* __restrict__ gwt,
    const float* __restrict__ bias, unsigned short* __restrict__ xb,
    float* __restrict__ logits_out, float* __restrict__ topk_f,
    int* __restrict__ topk_i, float* __restrict__ tw,
    int* __restrict__ counts) {
  int tid = threadIdx.x;
  int tbase = blockIdx.x * 8;
  // ---- fused x cast: coalesced float4 read, ushort4 write ----
  const float4* xsrc = (const float4*)(x + (size_t)tbase * 1024);
  ushort4* xbd = (ushort4*)(xb + (size_t)tbase * 1024);
#pragma unroll
  for (int p = 0; p < 8; ++p) {
    float4 v = xsrc[p * 256 + tid];
    ushort4 o;
    o.x = f2bf(v.x); o.y = f2bf(v.y); o.z = f2bf(v.z); o.w = f2bf(v.w);
    xbd[p * 256 + tid] = o;
  }
  // ---- dot products: lane (tok2, e) does full 1024-elem dot ----
  int lane = tid & 63, w = tid >> 6;
  int tok2 = lane >> 5, e = lane & 31, h = lane & 32;
  int t = tbase + w * 2 + tok2;
  const float* xrow = x + (size_t)t * 1024;
  float acc = 0.f;
#pragma unroll 8
  for (int j = 0; j < 256; ++j) {
    float4 xv = *(const float4*)(xrow + j * 4);            // 2 unique addrs/wave (broadcast)
    float4 wv = *(const float4*)(gwt + ((size_t)j * 32 + e) * 4);  // contiguous 512B across 32 lanes
    acc += xv.x * wv.x + xv.y * wv.y + xv.z * wv.z + xv.w * wv.w;
  }
  logits_out[(size_t)t * 32 + e] = acc;
  float sg = 1.f / (1.f + expf(-acc));
  float srt = sg + bias[e];
  // ---- group score: top-2 of 8 experts per group ----
  float m1 = srt, m2 = -1e30f;
#pragma unroll
  for (int off = 1; off < 8; off <<= 1) {
    float o1 = __shfl_xor(m1, off);
    float o2 = __shfl_xor(m2, off);
    if (o1 > m1) { m2 = fmaxf(m1, o2); m1 = o1; }
    else         { m2 = fmaxf(m2, o1); }
  }
  float gsv = m1 + m2;
  // ---- pick top-2 groups (strict >, lowest index wins ties) ----
  float q0 = __shfl(gsv, h + 0), q1 = __shfl(gsv, h + 8);
  float q2 = __shfl(gsv, h + 16), q3 = __shfl(gsv, h + 24);
  int ga = 0; float bv = q0;
  if (q1 > bv) { ga = 1; bv = q1; }
  if (q2 > bv) { ga = 2; bv = q2; }
  if (q3 > bv) { ga = 3; bv = q3; }
  int gb = -1; float bw = -1e30f;
  if (ga != 0) { gb = 0; bw = q0; }
  if (ga != 1 && q1 > bw) { gb = 1; bw = q1; }
  if (ga != 2 && q2 > bw) { gb = 2; bw = q2; }
  if (ga != 3 && q3 > bw) { gb = 3; bw = q3; }
  unsigned allowed = (0xFFu << (ga * 8)) | (0xFFu << (gb * 8));
  // ---- top-4 experts via packed 64-bit butterfly argmax within 32-lane half ----
  unsigned u = __float_as_uint(srt);
  u = (u & 0x80000000u) ? ~u : (u | 0x80000000u);
  unsigned long long key = ((unsigned long long)u << 32) | (unsigned)(31 - e);
  if (!((allowed >> e) & 1u)) key = 0ull;
  unsigned packed = 0;
  float wsum = 0.f;
#pragma unroll
  for (int k = 0; k < 4; ++k) {
    unsigned long long kk = key;
#pragma unroll
    for (int off = 1; off < 32; off <<= 1) {
      unsigned long long o = __shfl_xor(kk, off);
      if (o > kk) kk = o;
    }
    int ek = 31 - (int)(kk & 0xFFFFFFFFull);
    float sge = __shfl(sg, h + ek);
    wsum += sge;
    packed |= (unsigned)ek << (8 * k);
    if (e == ek) key = 0ull;
  }
  float scale = 2.5f / (wsum + 1e-20f);
  int kq = e & 3;
  int myek = (int)((packed >> (8 * kq)) & 0xFFu);
  float mysg = __shfl(sg, h + myek);
  if (e < 4) {
    int t4 = t * 4 + e;
    topk_i[t4] = myek;
    topk_f[t4] = (float)myek;
    tw[t4] = mysg * scale;
    atomicAdd(&counts[myek], 1);
  }
}

// ---------------- scan counts -> cursors + tile table ----------------
__global__ void build_tiles_kernel(const int* __restrict__ counts, int* __restrict__ cursor,
                                   int4* __restrict__ table, int* __restrict__ n_tiles) {
  if (threadIdx.x != 0) return;
  int base = 0, nt = 0;
  for (int e = 0; e < 32; ++e) {
    cursor[e] = base;
    int n = counts[e];
    for (int j = 0; j < n; j += 128) {
      int rem = n - j;
      table[nt] = make_int4(e, base + j, rem < 128 ? rem : 128, 0);
      ++nt;
    }
    base += n;
  }
  for (int j = 0; j < 32; ++j) {                 // shared expert rows: 16384..20479
    table[nt] = make_int4(32, NR_ROUTED + j * 128, 128, 0);
    ++nt;
  }
  *n_tiles = nt;
}

// ---------------- assign sorted slots ----------------
__global__ void assign_kernel(const int* __restrict__ topk_i, int* __restrict__ cursor,
                              int* __restrict__ perm, int* __restrict__ pos) {
  int idx = blockIdx.x * 256 + threadIdx.x;      // 20480 threads
  if (idx < NR_ROUTED) {
    int e = topk_i[idx];
    int p = atomicAdd(&cursor[e], 1);
    perm[p] = idx >> 2;                          // token id
    pos[idx] = p;
  } else {
    perm[idx] = idx - NR_ROUTED;                 // shared rows map to their token
  }
}

// ---------------- grouped GEMM, double-buffered k-loop ----------------
// 128x128 tile, BK=64, 4 waves, 4x4 frags of mfma_f32_16x16x32_bf16.
// Prefetch step s+1 into the other LDS buffer before computing step s: the compiler's
// vmcnt(0)-before-barrier then drains loads that had a full compute phase in flight.
// fuse_silu: B cols are interleaved (2p=gate,2p+1=up); epilogue computes silu(g)*u via
// __shfl_xor(.,1) and writes act[row][out_stride=512].
__global__ __launch_bounds__(256, 2) void gemm_kernel(
    const unsigned short* __restrict__ A, const unsigned short* __restrict__ B,
    unsigned short* __restrict__ C, const int* __restrict__ perm,
    const int4* __restrict__ table, const int* __restrict__ n_tiles,
    int K, int use_perm, int fuse_silu, int out_stride) {
  __shared__ unsigned short Al[2 * 128 * 64];
  __shared__ unsigned short Bl[2 * 128 * 64];
  if ((int)blockIdx.x >= *n_tiles) return;
  int4 te = table[blockIdx.x];
  int eidx = te.x, row_start = te.y, nrows = te.z;
  int n0 = blockIdx.y * 128;
  int tid = threadIdx.x, lane = tid & 63, wave = tid >> 6;
  int wr = wave >> 1, wc = wave & 1;

  const unsigned short* aBase[4];
  const unsigned short* bBase[4];
  int lOff[4];
#pragma unroll
  for (int i = 0; i < 4; ++i) {
    int s = wave * 64 + i * 256 + lane;          // seg index in [0,1024)
    int row = s >> 3, cseg = s & 7;
    int rowg = row_start + row;
    int tok = use_perm ? perm[rowg] : rowg;
    aBase[i] = A + (size_t)tok * K + cseg * 8;
    bBase[i] = B + (size_t)eidx * 1024 * K + (size_t)(n0 + row) * K + cseg * 8;
    lOff[i] = (wave * 64 + i * 256) * 8;
  }
  f32x4 acc[4][4];
  f32x4 z = {0.f, 0.f, 0.f, 0.f};
#pragma unroll
  for (int a = 0; a < 4; ++a)
#pragma unroll
    for (int b = 0; b < 4; ++b) acc[a][b] = z;

  int nsteps = K >> 6;
  // prologue: stage step 0 into buffer 0
#pragma unroll
  for (int i = 0; i < 4; ++i) {
    __builtin_amdgcn_global_load_lds(
        (const __attribute__((address_space(1))) unsigned int*)(aBase[i]),
        (__attribute__((address_space(3))) unsigned int*)&Al[lOff[i]], 16, 0, 0);
    __builtin_amdgcn_global_load_lds(
        (const __attribute__((address_space(1))) unsigned int*)(bBase[i]),
        (__attribute__((address_space(3))) unsigned int*)&Bl[lOff[i]], 16, 0, 0);
  }
  for (int s = 0; s < nsteps; ++s) {
    int cur = s & 1;
    const unsigned short* Ac = &Al[cur * (128 * 64)];
    const unsigned short* Bc = &Bl[cur * (128 * 64)];
    asm volatile("s_waitcnt vmcnt(0)" ::: "memory");
    __syncthreads();                              // buffer `cur` ready; prev compute done
    if (s + 1 < nsteps) {                         // prefetch next step into other buffer
      int ko = (s + 1) << 6;
      unsigned short* An = &Al[(cur ^ 1) * (128 * 64)];
      unsigned short* Bn = &Bl[(cur ^ 1) * (128 * 64)];
#pragma unroll
      for (int i = 0; i < 4; ++i) {
        __builtin_amdgcn_global_load_lds(
            (const __attribute__((address_space(1))) unsigned int*)(aBase[i] + ko),
            (__attribute__((address_space(3))) unsigned int*)&An[lOff[i]], 16, 0, 0);
        __builtin_amdgcn_global_load_lds(
            (const __attribute__((address_space(1))) unsigned int*)(bBase[i] + ko),
            (__attribute__((address_space(3))) unsigned int*)&Bn[lOff[i]], 16, 0, 0);
      }
    }
#pragma unroll
    for (int ks = 0; ks < 2; ++ks) {
      short8 af[4], bfr[4];
#pragma unroll
      for (int rf = 0; rf < 4; ++rf) {
        int m = wr * 64 + rf * 16 + (lane & 15);
        af[rf] = *(const short8*)&Ac[m * 64 + ks * 32 + (lane >> 4) * 8];
      }
#pragma unroll
      for (int cf = 0; cf < 4; ++cf) {
        int n = wc * 64 + cf * 16 + (lane & 15);
        bfr[cf] = *(const short8*)&Bc[n * 64 + ks * 32 + (lane >> 4) * 8];
      }
#pragma unroll
      for (int rf = 0; rf < 4; ++rf)
#pragma unroll
        for (int cf = 0; cf < 4; ++cf)
          acc[rf][cf] = __builtin_amdgcn_mfma_f32_16x16x32_bf16(af[rf], bfr[cf], acc[rf][cf], 0, 0, 0);
    }
  }
  // epilogue: C/D layout col=lane&15, row=(lane>>4)*4+reg
  int q = lane >> 4, cl = lane & 15;
  if (fuse_silu) {
    bool even = (cl & 1) == 0;
#pragma unroll
    for (int rf = 0; rf < 4; ++rf) {
#pragma unroll
      for (int r = 0; r < 4; ++r) {
        int rowl = wr * 64 + rf * 16 + q * 4 + r;
        size_t rowg = (size_t)(row_start + rowl);
#pragma unroll
        for (int cf = 0; cf < 4; ++cf) {
          float v = acc[rf][cf][r];
          float other = __shfl_xor(v, 1);         // all lanes execute
          if (even && rowl < nrows) {
            float g = v, u = other;
            float a = g / (1.f + expf(-g)) * u;
            int pcol = (n0 >> 1) + wc * 32 + cf * 8 + (cl >> 1);
            C[rowg * out_stride + pcol] = f2bf(a);
          }
        }
      }
    }
  } else {
#pragma unroll
    for (int rf = 0; rf < 4; ++rf) {
#pragma unroll
      for (int r = 0; r < 4; ++r) {
        int rowl = wr * 64 + rf * 16 + q * 4 + r;
        if (rowl < nrows) {
          size_t rowg = (size_t)(row_start + rowl);
#pragma unroll
          for (int cf = 0; cf < 4; ++cf) {
            int colg = n0 + wc * 64 + cf * 16 + cl;
            C[rowg * out_stride + colg] = f2bf(acc[rf][cf][r]);
          }
        }
      }
    }
  }
}

// ---------------- combine: y[t] = sum_k tw*out_s[pos] + out_s[shared] ----------------
__global__ void combine_kernel(const unsigned short* __restrict__ outs,
                               const int* __restrict__ pos, const float* __restrict__ tw,
                               float* __restrict__ y) {
  int t = blockIdx.x, tid = threadIdx.x;
  int c = tid * 4;
  ushort4 sv = *(const ushort4*)(outs + (size_t)(NR_ROUTED + t) * 1024 + c);
  float y0 = bf2f(sv.x), y1 = bf2f(sv.y), y2 = bf2f(sv.z), y3 = bf2f(sv.w);
#pragma unroll
  for (int k = 0; k < 4; ++k) {
    int p = pos[t * 4 + k];
    float w = tw[t * 4 + k];
    ushort4 v = *(const ushort4*)(outs + (size_t)p * 1024 + c);
    y0 += w * bf2f(v.x); y1 += w * bf2f(v.y); y2 += w * bf2f(v.z); y3 += w * bf2f(v.w);
  }
  float4 o = {y0, y1, y2, y3};
  *(float4*)(y + (size_t)t * 1024 + c) = o;
}

extern "C" void kernel_launch(void* const* d_in, const int* in_sizes, int n_in,
                              void* d_out, int out_size, void* d_ws, size_t ws_size,
                              hipStream_t stream) {
  const float* x       = (const float*)d_in[0];
  const float* gw      = (const float*)d_in[1];
  const float* bias    = (const float*)d_in[2];
  const float* w_gate  = (const float*)d_in[3];
  const float* w_up    = (const float*)d_in[4];
  const float* w_down  = (const float*)d_in[5];
  const float* ws_gate = (const float*)d_in[6];
  const float* ws_up   = (const float*)d_in[7];
  const float* ws_down = (const float*)d_in[8];

  char* ws = (char*)d_ws;
  size_t off = 0;
  auto alloc = [&](size_t bytes) {
    void* p = ws + off;
    off = (off + bytes + 255) & ~(size_t)255;
    return p;
  };
  unsigned short* wgu = (unsigned short*)alloc(33ull * 1024 * 1024 * 2);  // [e][interleaved g|u][k=1024]
  unsigned short* wd  = (unsigned short*)alloc(33ull * 1024 * 512 * 2);   // [e][n=1024][k=512]
  unsigned short* xb  = (unsigned short*)alloc(4096ull * 1024 * 2);
  unsigned short* gu  = (unsigned short*)alloc((size_t)NROWS * 1024 * 2); // out_s (gemm2 output)
  unsigned short* act = (unsigned short*)alloc((size_t)NROWS * 512 * 2);  // gemm1 fused-silu output
  float* gwt    = (float*)alloc(32 * 1024 * 4);
  int*   counts = (int*)alloc(32 * 4);
  int*   cursor = (int*)alloc(32 * 4);
  int*   ntiles = (int*)alloc(256);
  int4*  table  = (int4*)alloc(256 * 16);
  int*   perm   = (int*)alloc(NROWS * 4);
  int*   topk_i = (int*)alloc(NR_ROUTED * 4);
  int*   pos    = (int*)alloc(NR_ROUTED * 4);
  float* tw     = (float*)alloc(NR_ROUTED * 4);
  (void)ws_size; (void)in_sizes; (void)n_in; (void)out_size;

  float* out_y      = (float*)d_out;
  float* out_logits = out_y + 4096ull * 1024;
  float* out_topk   = out_logits + 4096ull * 32;

  hipMemsetAsync(counts, 0, 32 * 4, stream);
  gwt_kernel<<<32, 256, 0, stream>>>(gw, gwt);
  tcast_kernel<<<dim3(128, 33), 256, 0, stream>>>(w_gate, ws_gate, wgu, 1024, 512, 2, 0);
  tcast_kernel<<<dim3(128, 33), 256, 0, stream>>>(w_up,   ws_up,   wgu, 1024, 512, 2, 1);
  tcast_kernel<<<dim3(128, 33), 256, 0, stream>>>(w_down, ws_down, wd,  512, 1024, 1, 0);
  routing_kernel<<<512, 256, 0, stream>>>(x, gwt, bias, xb, out_logits, out_topk, topk_i, tw, counts);
  build_tiles_kernel<<<1, 64, 0, stream>>>(counts, cursor, table, ntiles);
  assign_kernel<<<80, 256, 0, stream>>>(topk_i, cursor, perm, pos);
  gemm_kernel<<<dim3(MAXTILES, 8), 256, 0, stream>>>(xb, wgu, act, perm, table, ntiles, 1024, 1, 1, 512);
  gemm_kernel<<<dim3(MAXTILES, 8), 256, 0, stream>>>(act, wd, gu, perm, table, ntiles, 512, 0, 0, 1024);
  combine_kernel<<<4096, 256, 0, stream>>>(gu, pos, tw, out_y);
}

// Round 5
// 463.730 us; speedup vs baseline: 1.1050x; 1.1050x over previous
//
#include <hip/hip_runtime.h>
#include <stdint.h>

typedef __attribute__((ext_vector_type(8))) short short8;   // 8 bf16 in 4 VGPRs
typedef __attribute__((ext_vector_type(4))) float f32x4;

#define NR_ROUTED 16384      // T * TOP_K
#define NROWS     20480      // + T shared rows
#define MAXTILES  192

__device__ __forceinline__ float bf2f(unsigned short h) {
  return __uint_as_float(((unsigned)h) << 16);
}
__device__ __forceinline__ unsigned short f2bf(float f) {
  unsigned u = __float_as_uint(f);
  u = (u + 0x7FFFu + ((u >> 16) & 1u)) >> 16;   // round-to-nearest-even
  return (unsigned short)u;
}

// ------------- transpose + cast weights: [e][K][N] fp32 -> bf16 [e][1024 rows][Kd] -------------
// dst row = e*1024 + (n0+n)*n_mul + n_add  (n_mul=2 interleaves gate/up columns for fused silu)
__global__ void tcast_kernel(const float* __restrict__ src0, const float* __restrict__ src1,
                             unsigned short* __restrict__ dst, int Kd, int Nd,
                             int n_mul, int n_add) {
  __shared__ float tl[64][65];
  int tilesK = Kd >> 6;
  int tk = blockIdx.x % tilesK, tn = blockIdx.x / tilesK;
  int e = blockIdx.y;
  const float* src = (e < 32) ? (src0 + (size_t)e * Kd * Nd) : src1;
  int k0 = tk * 64, n0 = tn * 64;
  int tid = threadIdx.x;
#pragma unroll
  for (int p = 0; p < 4; ++p) {
    int f = p * 256 + tid;
    int r = f >> 4, c4 = (f & 15) * 4;
    float4 v = *(const float4*)(src + (size_t)(k0 + r) * Nd + n0 + c4);
    tl[c4 + 0][r] = v.x; tl[c4 + 1][r] = v.y; tl[c4 + 2][r] = v.z; tl[c4 + 3][r] = v.w;
  }
  __syncthreads();
#pragma unroll
  for (int p = 0; p < 4; ++p) {
    int f = p * 256 + tid;
    int n = f >> 4, kc = (f & 15) * 4;
    ushort4 o;
    o.x = f2bf(tl[n][kc + 0]); o.y = f2bf(tl[n][kc + 1]);
    o.z = f2bf(tl[n][kc + 2]); o.w = f2bf(tl[n][kc + 3]);
    *(ushort4*)(dst + ((size_t)e * 1024 + (size_t)(n0 + n) * n_mul + n_add) * Kd + k0 + kc) = o;
  }
}

// ---------------- gate-weight transpose: gwt[j4][e] = float4(gw[e][j4*4..+3]) ----------------
__global__ void gwt_kernel(const float* __restrict__ gw, float* __restrict__ gwt) {
  int idx = blockIdx.x * 256 + threadIdx.x;      // 8192 threads
  int e = idx & 31, j4 = idx >> 5;
  float4 v = *(const float4*)(gw + (size_t)e * 1024 + j4 * 4);
  *(float4*)(gwt + ((size_t)j4 * 32 + e) * 4) = v;
}

// ---------------- routing: wave = 2 tokens, lane = (tok2<<5)|expert, register top-k ----------------
__global__ __launch_bounds__(256) void routing_kernel(
    const float* __restrict__ x, const float* __restrict__ gwt,
    const float* __restrict__ bias, unsigned short* __restrict__ xb,
    float* __restrict__ logits_out, float* __restrict__ topk_f,
    int* __restrict__ topk_i, float* __restrict__ tw,
    int* __restrict__ counts) {
  int tid = threadIdx.x;
  int tbase = blockIdx.x * 8;
  // ---- fused x cast: coalesced float4 read, ushort4 write ----
  const float4* xsrc = (const float4*)(x + (size_t)tbase * 1024);
  ushort4* xbd = (ushort4*)(xb + (size_t)tbase * 1024);
#pragma unroll
  for (int p = 0; p < 8; ++p) {
    float4 v = xsrc[p * 256 + tid];
    ushort4 o;
    o.x = f2bf(v.x); o.y = f2bf(v.y); o.z = f2bf(v.z); o.w = f2bf(v.w);
    xbd[p * 256 + tid] = o;
  }
  // ---- dot products: lane (tok2, e) does full 1024-elem dot ----
  int lane = tid & 63, w = tid >> 6;
  int tok2 = lane >> 5, e = lane & 31, h = lane & 32;
  int t = tbase + w * 2 + tok2;
  const float* xrow = x + (size_t)t * 1024;
  float acc = 0.f;
#pragma unroll 8
  for (int j = 0; j < 256; ++j) {
    float4 xv = *(const float4*)(xrow + j * 4);            // 2 unique addrs/wave (broadcast)
    float4 wv = *(const float4*)(gwt + ((size_t)j * 32 + e) * 4);  // contiguous 512B across 32 lanes
    acc += xv.x * wv.x + xv.y * wv.y + xv.z * wv.z + xv.w * wv.w;
  }
  logits_out[(size_t)t * 32 + e] = acc;
  float sg = 1.f / (1.f + expf(-acc));
  float srt = sg + bias[e];
  // ---- group score: top-2 of 8 experts per group ----
  float m1 = srt, m2 = -1e30f;
#pragma unroll
  for (int off = 1; off < 8; off <<= 1) {
    float o1 = __shfl_xor(m1, off);
    float o2 = __shfl_xor(m2, off);
    if (o1 > m1) { m2 = fmaxf(m1, o2); m1 = o1; }
    else         { m2 = fmaxf(m2, o1); }
  }
  float gsv = m1 + m2;
  // ---- pick top-2 groups (strict >, lowest index wins ties) ----
  float q0 = __shfl(gsv, h + 0), q1 = __shfl(gsv, h + 8);
  float q2 = __shfl(gsv, h + 16), q3 = __shfl(gsv, h + 24);
  int ga = 0; float bv = q0;
  if (q1 > bv) { ga = 1; bv = q1; }
  if (q2 > bv) { ga = 2; bv = q2; }
  if (q3 > bv) { ga = 3; bv = q3; }
  int gb = -1; float bw = -1e30f;
  if (ga != 0) { gb = 0; bw = q0; }
  if (ga != 1 && q1 > bw) { gb = 1; bw = q1; }
  if (ga != 2 && q2 > bw) { gb = 2; bw = q2; }
  if (ga != 3 && q3 > bw) { gb = 3; bw = q3; }
  unsigned allowed = (0xFFu << (ga * 8)) | (0xFFu << (gb * 8));
  // ---- top-4 experts via packed 64-bit butterfly argmax within 32-lane half ----
  unsigned u = __float_as_uint(srt);
  u = (u & 0x80000000u) ? ~u : (u | 0x80000000u);
  unsigned long long key = ((unsigned long long)u << 32) | (unsigned)(31 - e);
  if (!((allowed >> e) & 1u)) key = 0ull;
  unsigned packed = 0;
  float wsum = 0.f;
#pragma unroll
  for (int k = 0; k < 4; ++k) {
    unsigned long long kk = key;
#pragma unroll
    for (int off = 1; off < 32; off <<= 1) {
      unsigned long long o = __shfl_xor(kk, off);
      if (o > kk) kk = o;
    }
    int ek = 31 - (int)(kk & 0xFFFFFFFFull);
    float sge = __shfl(sg, h + ek);
    wsum += sge;
    packed |= (unsigned)ek << (8 * k);
    if (e == ek) key = 0ull;
  }
  float scale = 2.5f / (wsum + 1e-20f);
  int kq = e & 3;
  int myek = (int)((packed >> (8 * kq)) & 0xFFu);
  float mysg = __shfl(sg, h + myek);
  if (e < 4) {
    int t4 = t * 4 + e;
    topk_i[t4] = myek;
    topk_f[t4] = (float)myek;
    tw[t4] = mysg * scale;
    atomicAdd(&counts[myek], 1);
  }
}

// ---------------- scan counts -> cursors + tile table (single wave, shuffle scans) ----------------
__global__ void build_tiles_kernel(const int* __restrict__ counts, int* __restrict__ cursor,
                                   int4* __restrict__ table, int* __restrict__ n_tiles) {
  int lane = threadIdx.x;                        // 64 threads = one wave
  int c = (lane < 32) ? counts[lane] : 0;
  int incl = c;
#pragma unroll
  for (int off = 1; off < 32; off <<= 1) {
    int v = __shfl_up(incl, off);
    if (lane >= off) incl += v;
  }
  int base = incl - c;                           // exclusive prefix of counts
  int nt_e = (c + 127) >> 7;
  int tincl = nt_e;
#pragma unroll
  for (int off = 1; off < 32; off <<= 1) {
    int v = __shfl_up(tincl, off);
    if (lane >= off) tincl += v;
  }
  int toff = tincl - nt_e;                       // exclusive prefix of tile counts
  int tot = __shfl(tincl, 31);                   // total routed tiles
  if (lane < 32) {
    cursor[lane] = base;
    for (int j = 0; j < nt_e; ++j) {
      int rem = c - j * 128;
      table[toff + j] = make_int4(lane, base + j * 128, rem < 128 ? rem : 128, 0);
    }
    table[tot + lane] = make_int4(32, NR_ROUTED + lane * 128, 128, 0);  // shared-expert tiles
  }
  if (lane == 0) *n_tiles = tot + 32;
}

// ---------------- assign sorted slots ----------------
__global__ void assign_kernel(const int* __restrict__ topk_i, int* __restrict__ cursor,
                              int* __restrict__ perm, int* __restrict__ pos) {
  int idx = blockIdx.x * 256 + threadIdx.x;      // 20480 threads
  if (idx < NR_ROUTED) {
    int e = topk_i[idx];
    int p = atomicAdd(&cursor[e], 1);
    perm[p] = idx >> 2;                          // token id
    pos[idx] = p;
  } else {
    perm[idx] = idx - NR_ROUTED;                 // shared rows map to their token
  }
}

// ---------------- grouped GEMM, single-buffer k-loop + XOR-swizzled LDS ----------------
// 128x128 tile, BK=64, 4 waves, 4x4 frags of mfma_f32_16x16x32_bf16.
// LDS row stride = 128B = 32 banks, so unswizzled fragment reads are 16-way bank
// conflicts (1.68e7 conflict cycles/dispatch measured). global_load_lds forces dest
// = base + lane*16B, so the swizzle is applied by permuting WHICH k-segment each lane
// fetches (cd = c ^ (row&7)); fragment reads XOR the segment index back. Sources stay
// within the same 128B row window -> coalescing preserved.
// Grid is (8 n-blocks, tiles): XCD = linear%8 = n-block, so all tiles of one n-block
// share an XCD and same-expert consecutive tiles hit its L2 (kills ~4x weight refetch).
__global__ __launch_bounds__(256, 2) void gemm_kernel(
    const unsigned short* __restrict__ A, const unsigned short* __restrict__ B,
    unsigned short* __restrict__ C, const int* __restrict__ perm,
    const int4* __restrict__ table, const int* __restrict__ n_tiles,
    int K, int use_perm, int fuse_silu, int out_stride) {
  __shared__ unsigned short Al[128 * 64];
  __shared__ unsigned short Bl[128 * 64];
  if ((int)blockIdx.y >= *n_tiles) return;
  int4 te = table[blockIdx.y];
  int eidx = te.x, row_start = te.y, nrows = te.z;
  int n0 = blockIdx.x * 128;
  int tid = threadIdx.x, lane = tid & 63, wave = tid >> 6;
  int wr = wave >> 1, wc = wave & 1;

  const unsigned short* aBase[4];
  const unsigned short* bBase[4];
  int lOff[4];
#pragma unroll
  for (int i = 0; i < 4; ++i) {
    int s = wave * 64 + i * 256 + lane;          // seg index in [0,1024)
    int row = s >> 3, c = s & 7;
    int cd = c ^ (row & 7);                      // xor-swizzle: lane fetches permuted segment
    int rowg = row_start + row;
    int tok = use_perm ? perm[rowg] : rowg;
    aBase[i] = A + (size_t)tok * K + cd * 8;
    bBase[i] = B + (size_t)eidx * 1024 * K + (size_t)(n0 + row) * K + cd * 8;
    lOff[i] = s * 8;
  }
  f32x4 acc[4][4];
  f32x4 z = {0.f, 0.f, 0.f, 0.f};
#pragma unroll
  for (int a = 0; a < 4; ++a)
#pragma unroll
    for (int b = 0; b < 4; ++b) acc[a][b] = z;

  int mrow = wr * 64 + (lane & 15);              // fragment row base (A)
  int nrow = wc * 64 + (lane & 15);              // fragment row base (B)
  int qq = lane >> 4;

  for (int k0 = 0; k0 < K; k0 += 64) {
#pragma unroll
    for (int i = 0; i < 4; ++i) {
      __builtin_amdgcn_global_load_lds(
          (const __attribute__((address_space(1))) unsigned int*)(aBase[i] + k0),
          (__attribute__((address_space(3))) unsigned int*)&Al[lOff[i]], 16, 0, 0);
      __builtin_amdgcn_global_load_lds(
          (const __attribute__((address_space(1))) unsigned int*)(bBase[i] + k0),
          (__attribute__((address_space(3))) unsigned int*)&Bl[lOff[i]], 16, 0, 0);
    }
    asm volatile("s_waitcnt vmcnt(0)" ::: "memory");
    __syncthreads();
#pragma unroll
    for (int ks = 0; ks < 2; ++ks) {
      int j = ks * 4 + qq;                       // data k-segment
      short8 af[4], bfr[4];
#pragma unroll
      for (int rf = 0; rf < 4; ++rf) {
        int m = mrow + rf * 16;
        af[rf] = *(const short8*)&Al[m * 64 + (j ^ (m & 7)) * 8];
      }
#pragma unroll
      for (int cf = 0; cf < 4; ++cf) {
        int n = nrow + cf * 16;
        bfr[cf] = *(const short8*)&Bl[n * 64 + (j ^ (n & 7)) * 8];
      }
#pragma unroll
      for (int rf = 0; rf < 4; ++rf)
#pragma unroll
        for (int cf = 0; cf < 4; ++cf)
          acc[rf][cf] = __builtin_amdgcn_mfma_f32_16x16x32_bf16(af[rf], bfr[cf], acc[rf][cf], 0, 0, 0);
    }
    __syncthreads();
  }
  // epilogue: C/D layout col=lane&15, row=(lane>>4)*4+reg
  int q = lane >> 4, cl = lane & 15;
  if (fuse_silu) {
    bool even = (cl & 1) == 0;
#pragma unroll
    for (int rf = 0; rf < 4; ++rf) {
#pragma unroll
      for (int r = 0; r < 4; ++r) {
        int rowl = wr * 64 + rf * 16 + q * 4 + r;
        size_t rowg = (size_t)(row_start + rowl);
#pragma unroll
        for (int cf = 0; cf < 4; ++cf) {
          float v = acc[rf][cf][r];
          float other = __shfl_xor(v, 1);         // all lanes execute
          if (even && rowl < nrows) {
            float g = v, u = other;
            float a = g / (1.f + expf(-g)) * u;
            int pcol = (n0 >> 1) + wc * 32 + cf * 8 + (cl >> 1);
            C[rowg * out_stride + pcol] = f2bf(a);
          }
        }
      }
    }
  } else {
#pragma unroll
    for (int rf = 0; rf < 4; ++rf) {
#pragma unroll
      for (int r = 0; r < 4; ++r) {
        int rowl = wr * 64 + rf * 16 + q * 4 + r;
        if (rowl < nrows) {
          size_t rowg = (size_t)(row_start + rowl);
#pragma unroll
          for (int cf = 0; cf < 4; ++cf) {
            int colg = n0 + wc * 64 + cf * 16 + cl;
            C[rowg * out_stride + colg] = f2bf(acc[rf][cf][r]);
          }
        }
      }
    }
  }
}

// ---------------- combine: y[t] = sum_k tw*out_s[pos] + out_s[shared] ----------------
__global__ void combine_kernel(const unsigned short* __restrict__ outs,
                               const int* __restrict__ pos, const float* __restrict__ tw,
                               float* __restrict__ y) {
  int t = blockIdx.x, tid = threadIdx.x;
  int c = tid * 4;
  ushort4 sv = *(const ushort4*)(outs + (size_t)(NR_ROUTED + t) * 1024 + c);
  float y0 = bf2f(sv.x), y1 = bf2f(sv.y), y2 = bf2f(sv.z), y3 = bf2f(sv.w);
#pragma unroll
  for (int k = 0; k < 4; ++k) {
    int p = pos[t * 4 + k];
    float w = tw[t * 4 + k];
    ushort4 v = *(const ushort4*)(outs + (size_t)p * 1024 + c);
    y0 += w * bf2f(v.x); y1 += w * bf2f(v.y); y2 += w * bf2f(v.z); y3 += w * bf2f(v.w);
  }
  float4 o = {y0, y1, y2, y3};
  *(float4*)(y + (size_t)t * 1024 + c) = o;
}

extern "C" void kernel_launch(void* const* d_in, const int* in_sizes, int n_in,
                              void* d_out, int out_size, void* d_ws, size_t ws_size,
                              hipStream_t stream) {
  const float* x       = (const float*)d_in[0];
  const float* gw      = (const float*)d_in[1];
  const float* bias    = (const float*)d_in[2];
  const float* w_gate  = (const float*)d_in[3];
  const float* w_up    = (const float*)d_in[4];
  const float* w_down  = (const float*)d_in[5];
  const float* ws_gate = (const float*)d_in[6];
  const float* ws_up   = (const float*)d_in[7];
  const float* ws_down = (const float*)d_in[8];

  char* ws = (char*)d_ws;
  size_t off = 0;
  auto alloc = [&](size_t bytes) {
    void* p = ws + off;
    off = (off + bytes + 255) & ~(size_t)255;
    return p;
  };
  unsigned short* wgu = (unsigned short*)alloc(33ull * 1024 * 1024 * 2);  // [e][interleaved g|u][k=1024]
  unsigned short* wd  = (unsigned short*)alloc(33ull * 1024 * 512 * 2);   // [e][n=1024][k=512]
  unsigned short* xb  = (unsigned short*)alloc(4096ull * 1024 * 2);
  unsigned short* gu  = (unsigned short*)alloc((size_t)NROWS * 1024 * 2); // out_s (gemm2 output)
  unsigned short* act = (unsigned short*)alloc((size_t)NROWS * 512 * 2);  // gemm1 fused-silu output
  float* gwt    = (float*)alloc(32 * 1024 * 4);
  int*   counts = (int*)alloc(32 * 4);
  int*   cursor = (int*)alloc(32 * 4);
  int*   ntiles = (int*)alloc(256);
  int4*  table  = (int4*)alloc(256 * 16);
  int*   perm   = (int*)alloc(NROWS * 4);
  int*   topk_i = (int*)alloc(NR_ROUTED * 4);
  int*   pos    = (int*)alloc(NR_ROUTED * 4);
  float* tw     = (float*)alloc(NR_ROUTED * 4);
  (void)ws_size; (void)in_sizes; (void)n_in; (void)out_size;

  float* out_y      = (float*)d_out;
  float* out_logits = out_y + 4096ull * 1024;
  float* out_topk   = out_logits + 4096ull * 32;

  hipMemsetAsync(counts, 0, 32 * 4, stream);
  gwt_kernel<<<32, 256, 0, stream>>>(gw, gwt);
  tcast_kernel<<<dim3(128, 33), 256, 0, stream>>>(w_gate, ws_gate, wgu, 1024, 512, 2, 0);
  tcast_kernel<<<dim3(128, 33), 256, 0, stream>>>(w_up,   ws_up,   wgu, 1024, 512, 2, 1);
  tcast_kernel<<<dim3(128, 33), 256, 0, stream>>>(w_down, ws_down, wd,  512, 1024, 1, 0);
  routing_kernel<<<512, 256, 0, stream>>>(x, gwt, bias, xb, out_logits, out_topk, topk_i, tw, counts);
  build_tiles_kernel<<<1, 64, 0, stream>>>(counts, cursor, table, ntiles);
  assign_kernel<<<80, 256, 0, stream>>>(topk_i, cursor, perm, pos);
  gemm_kernel<<<dim3(8, MAXTILES), 256, 0, stream>>>(xb, wgu, act, perm, table, ntiles, 1024, 1, 1, 512);
  gemm_kernel<<<dim3(8, MAXTILES), 256, 0, stream>>>(act, wd, gu, perm, table, ntiles, 512, 0, 0, 1024);
  combine_kernel<<<4096, 256, 0, stream>>>(gu, pos, tw, out_y);
}